// Round 11
// baseline (327.941 us; speedup 1.0000x reference)
//
#include <hip/hip_runtime.h>
#include <stdint.h>
#include <string.h>

#define BB 256
#define TT 2048
#define DD 64
#define CC 128         // chunks per chain (SS=16 verified in R8: passed, absmax 64)
#define SS 16          // steps per chunk; each wave interleaves TWO chunks
#define C_L2E 1.44269504f
#define C_LN2 0.69314718f
// log2(1 + 2^-9): compensates bf16 truncation bias of the pack, folded into exp
#define C_BIAS 0.0028174f

typedef short sh8  __attribute__((ext_vector_type(8)));
typedef float f32x4 __attribute__((ext_vector_type(4)));

union BU { sh8 v8; unsigned int u[4]; unsigned short s[8]; };

__device__ __forceinline__ float expf_fast(float x) { return __builtin_amdgcn_exp2f(x * C_L2E); }
__device__ __forceinline__ unsigned short bf16rne(float x) {
    unsigned int u = __float_as_uint(x);
    u += 0x7FFF + ((u >> 16) & 1u);
    return (unsigned short)(u >> 16);
}
__device__ __forceinline__ unsigned int pkbf(float hi, float lo) {
    return __builtin_amdgcn_perm(__float_as_uint(hi), __float_as_uint(lo), 0x07060302u);
}

#define DPPMAX(x, ctrl, rm, bm) { int _xi = __float_as_int(x);                              \
    int _yi = __builtin_amdgcn_update_dpp(_xi, _xi, ctrl, rm, bm, false);                   \
    x = fmaxf(x, __int_as_float(_yi)); }

// ---------- kernel 0: lengths from mask only (verified R4-R10) ----------
__global__ __launch_bounds__(256) void crf_len(
    const int* __restrict__ mask, int* __restrict__ wsL)
{
    __shared__ int r4[4];
    const int c = blockIdx.x, tid = threadIdx.x;
    const int4* mrow = (const int4*)(mask + (size_t)c * TT);
    int4 a = mrow[tid * 2], b = mrow[tid * 2 + 1];
    int s = a.x + a.y + a.z + a.w + b.x + b.y + b.z + b.w;
#pragma unroll
    for (int xm = 32; xm >= 1; xm >>= 1) s += __shfl_xor(s, xm, 64);
    if ((tid & 63) == 0) r4[tid >> 6] = s;
    __syncthreads();
    if (tid == 0) wsL[c] = TT - (r4[0] + r4[1] + r4[2] + r4[3]);   // prefix mask: L = #zeros
}

// ---------- kernel 1a: label extraction, pure TLP streaming over y (verified R7-R10) ----------
__global__ __launch_bounds__(256) void crf_lab(
    const int* __restrict__ y, unsigned char* __restrict__ labsG)
{
    const int tid = threadIdx.x;
    const int g = tid & 15, sub = tid >> 4;              // sub 0..15
    const size_t base = (size_t)blockIdx.x * 64;         // first token of block
    int4 v[4];
#pragma unroll
    for (int k = 0; k < 4; ++k)
        v[k] = ((const int4*)y)[(base + (size_t)k * 16 + sub) * 16 + g];  // 1 KB/wave/k
#pragma unroll
    for (int k = 0; k < 4; ++k) {
        int s = v[k].x * (4 * g) + v[k].y * (4 * g + 1)
              + v[k].z * (4 * g + 2) + v[k].w * (4 * g + 3);
#pragma unroll
        for (int xm = 1; xm <= 8; xm <<= 1) s += __shfl_xor(s, xm, 16);
        if (g == 0) labsG[base + k * 16 + sub] = (unsigned char)s;
    }
}

// ---------- kernel 1b: score gather (after probe: p is L3-resident; verified R7-R10) ----------
__global__ __launch_bounds__(256) void crf_gth(
    const float* __restrict__ p, const unsigned char* __restrict__ labsG,
    const int* __restrict__ mask, const float* __restrict__ tr,
    float* __restrict__ wsS)
{
    __shared__ float redf[4];
    const int c = blockIdx.y, t0 = blockIdx.x * 256;
    const int tid = threadIdx.x;
    const size_t cb = (size_t)c * TT;
    const int tt = t0 + tid;

    const int m0 = mask[cb + tt];
    const int m1 = (tt + 1 < TT) ? mask[cb + tt + 1] : 1;
    const int l0 = labsG[cb + tt];

    float s = 0.f;
    if (m0 == 0)                                  // emission for valid token
        s += p[(cb + tt) * DD + l0];
    if (m1 == 0) {                                // pair (t,t+1) valid
        const int l1 = labsG[cb + tt + 1];
        s += tr[l0 * DD + l1];
    }
#pragma unroll
    for (int xm = 32; xm >= 1; xm >>= 1) s += __shfl_xor(s, xm, 64);
    if ((tid & 63) == 0) redf[tid >> 6] = s;
    __syncthreads();
    if (tid == 0)
        atomicAdd(&wsS[c], redf[0] + redf[1] + redf[2] + redf[3]);
}

// ---------- kernel 2: rank-1 chunk probes, TWO chunks interleaved per wave ----------
// Evidence (R8/R9/R10 PMC): probe wall-step ~2500 cyc with only ~270 busy (VALU 22%,
// MFMA 4%) -- each wave stalls ~95% advancing ONE serial recurrence, invariant to issue
// depth (R0 d4 == R9 d2), wave count (R8) and coalescing (R10). Fix: each wave advances
// TWO independent chunks (icA, icB = icA+1) of its 16 chains; substeps interleaved
// A,B,A,B so one chain's stall hides under the other's compute/loads. Per-wave serial
// steps 32 -> 16 at 2x chains/SIMD. A-fragments + mL shared (direction-only); per-chunk
// state xsA/xsB, erA/erB (depth-2, statically indexed), sigA/sigB. Unified loop range =
// chunk A's window (superset of B's); per-chain 'act' predicate keeps B's frozen steps
// correct (xs stays identity -> stored probe = ones, sig 0: same as the old skip path).
__global__ __launch_bounds__(256) void crf_probe(
    const float* __restrict__ p, const float* __restrict__ tr,
    const int* __restrict__ wsL,
    unsigned short* __restrict__ wsA, unsigned short* __restrict__ wsB, int* __restrict__ wsSig)
{
    const int tid = threadIdx.x, w = tid >> 6, lane = tid & 63;
    const int q = lane >> 4, ml = lane & 15;
    const int cg = blockIdx.x;
    const int icA = blockIdx.y * 4 + (w >> 1) * 2;   // wave pair handles chunks icA, icA+1
    const int icB = icA + 1;
    const int bwd = w & 1;
    const int c = cg * 16 + ml;
    const int Lml = wsL[c];
    const int t0A = icA * SS, t1A = t0A + SS;
    const int t0B = icB * SS, t1B = t0B + SS;
    const int tsA = (icA == 0) ? 1 : t0A;
    const int tsB = t0B;
    const float* prow = p + (size_t)c * TT * DD;

    // A fragments: fwd A = W^T (exp(T[lam][row])), bwd A = W (exp(T[row][lam]))
    BU A[4][2];
#pragma unroll
    for (int mt = 0; mt < 4; ++mt)
#pragma unroll
        for (int kt2 = 0; kt2 < 2; ++kt2)
#pragma unroll
            for (int j = 0; j < 8; ++j) {
                int lam = 32 * kt2 + 16 * (j >> 2) + 4 * q + (j & 3);
                float tv = bwd ? tr[(16 * mt + ml) * DD + lam] : tr[lam * DD + 16 * mt + ml];
                A[mt][kt2].s[j] = (short)bf16rne(expf_fast(tv));
            }

    // state xs[idx], idx = kt2*8 + h*4 + r  <->  lam = 32kt2+16h+4q+r
    float xsA[16], xsB[16];
    if (!bwd && icA == 0) {          // exact start: u0 = exp(p[c,0,:])
#pragma unroll
        for (int k = 0; k < 4; ++k) {
            f32x4 v = *(const f32x4*)(prow + 16 * k + 4 * q);
#pragma unroll
            for (int r = 0; r < 4; ++r)
                xsA[(k >> 1) * 8 + (k & 1) * 4 + r] = __builtin_amdgcn_exp2f(fmaf(v[r], C_L2E, C_BIAS));
        }
    } else {
#pragma unroll
        for (int i = 0; i < 16; ++i) xsA[i] = 1.0f;
    }
#pragma unroll
    for (int i = 0; i < 16; ++i) xsB[i] = 1.0f;

    // wave max of L -> unified skip range (chunk A's window is the superset)
    int mL = Lml;
#pragma unroll
    for (int xm = 32; xm >= 1; xm >>= 1) { int o = __shfl_xor(mL, xm, 64); mL = o > mL ? o : mL; }
    int ibegU = 0, iendU = SS;
    if (!bwd) { int ir = mL - t0A; if (ir < 0) ir = 0; iendU = (ir + 3) & ~3; if (iendU > SS) iendU = SS; }
    else      { int ir = t1A - mL; if (ir < 0) ir = 0; ibegU = ir & ~3; if (ibegU > SS) ibegU = SS; }

    int sigA = 0, sigB = 0;
    const f32x4 z4 = {0.f, 0.f, 0.f, 0.f};

    if (ibegU < iendU) {
        f32x4 erA[2][4], erB[2][4];
#pragma unroll
        for (int s = 0; s < 2; ++s) {                 // preload steps ibegU, ibegU+1 (both chunks)
            int i = ibegU + s;
            int tA = bwd ? (t1A - 1 - i) : (t0A + i);
            int tB = bwd ? (t1B - 1 - i) : (t0B + i);
#pragma unroll
            for (int k = 0; k < 4; ++k) {
                erA[s][k] = *(const f32x4*)(prow + (size_t)tA * DD + 16 * k + 4 * q);
                erB[s][k] = *(const f32x4*)(prow + (size_t)tB * DD + 16 * k + 4 * q);
            }
        }

// One substep of one chunk X at parity SE (er slot SE&1, statically indexed).
#define PSTEP(X, SE)                                                                        \
        {                                                                                   \
            const int i = ib + SE;                                                          \
            const int t = bwd ? (t1##X - 1 - i) : (t0##X + i);                              \
            const bool act = (t >= ts##X) && (t < Lml);                                     \
            float ee[4][4];                                                                 \
            _Pragma("unroll")                                                               \
            for (int k = 0; k < 4; ++k)                                                     \
                _Pragma("unroll")                                                           \
                for (int r = 0; r < 4; ++r)                                                 \
                    ee[k][r] = __builtin_amdgcn_exp2f(fmaf(er##X[SE & 1][k][r], C_L2E, C_BIAS)); \
            {   /* refill er slot with step i+2 */                                          \
                int ipf = i + 2;                                                            \
                int tpf = bwd ? (t1##X - 1 - ipf) : (t0##X + ipf);                          \
                if (tpf < t0##X) tpf = t0##X;                                               \
                if (tpf > t1##X - 1) tpf = t1##X - 1;                                       \
                _Pragma("unroll")                                                           \
                for (int k = 0; k < 4; ++k)                                                 \
                    er##X[SE & 1][k] = *(const f32x4*)(prow + (size_t)tpf * DD + 16 * k + 4 * q); \
            }                                                                               \
            float cand[16];                                                                 \
            BU Bf[2];                                                                       \
            f32x4 acc[4];                                                                   \
            if (!bwd) {     /* u' = diag(e) W^T u : scale on output */                      \
                _Pragma("unroll")                                                           \
                for (int kt2 = 0; kt2 < 2; ++kt2)                                           \
                    _Pragma("unroll")                                                       \
                    for (int jj = 0; jj < 4; ++jj)                                          \
                        Bf[kt2].u[jj] = pkbf(xs##X[kt2 * 8 + 2 * jj + 1], xs##X[kt2 * 8 + 2 * jj]); \
                _Pragma("unroll")                                                           \
                for (int mt = 0; mt < 4; ++mt) {                                            \
                    acc[mt] = __builtin_amdgcn_mfma_f32_16x16x32_bf16(A[mt][0].v8, Bf[0].v8, z4, 0, 0, 0); \
                    acc[mt] = __builtin_amdgcn_mfma_f32_16x16x32_bf16(A[mt][1].v8, Bf[1].v8, acc[mt], 0, 0, 0); \
                }                                                                           \
                _Pragma("unroll")                                                           \
                for (int mt = 0; mt < 4; ++mt)                                              \
                    _Pragma("unroll")                                                       \
                    for (int r = 0; r < 4; ++r)                                             \
                        cand[(mt >> 1) * 8 + (mt & 1) * 4 + r] = acc[mt][r] * ee[mt][r];    \
            } else {        /* w' = W (e .* w) : scale on input */                          \
                float xsc[16];                                                              \
                _Pragma("unroll")                                                           \
                for (int kt2 = 0; kt2 < 2; ++kt2)                                           \
                    _Pragma("unroll")                                                       \
                    for (int h = 0; h < 2; ++h)                                             \
                        _Pragma("unroll")                                                   \
                        for (int r = 0; r < 4; ++r)                                         \
                            xsc[kt2 * 8 + h * 4 + r] = xs##X[kt2 * 8 + h * 4 + r] * ee[2 * kt2 + h][r]; \
                _Pragma("unroll")                                                           \
                for (int kt2 = 0; kt2 < 2; ++kt2)                                           \
                    _Pragma("unroll")                                                       \
                    for (int jj = 0; jj < 4; ++jj)                                          \
                        Bf[kt2].u[jj] = pkbf(xsc[kt2 * 8 + 2 * jj + 1], xsc[kt2 * 8 + 2 * jj]); \
                _Pragma("unroll")                                                           \
                for (int mt = 0; mt < 4; ++mt) {                                            \
                    acc[mt] = __builtin_amdgcn_mfma_f32_16x16x32_bf16(A[mt][0].v8, Bf[0].v8, z4, 0, 0, 0); \
                    acc[mt] = __builtin_amdgcn_mfma_f32_16x16x32_bf16(A[mt][1].v8, Bf[1].v8, acc[mt], 0, 0, 0); \
                }                                                                           \
                _Pragma("unroll")                                                           \
                for (int mt = 0; mt < 4; ++mt)                                              \
                    _Pragma("unroll")                                                       \
                    for (int r = 0; r < 4; ++r)                                             \
                        cand[(mt >> 1) * 8 + (mt & 1) * 4 + r] = acc[mt][r];                \
            }                                                                               \
            if (SE == 3) {   /* wave-uniform pow-2 renorm, per-chain sig */                 \
                float mx = fabsf(cand[0]);                                                  \
                _Pragma("unroll")                                                           \
                for (int i2 = 1; i2 < 16; ++i2) mx = fmaxf(mx, fabsf(cand[i2]));            \
                DPPMAX(mx, 0x111, 0xF, 0xF); DPPMAX(mx, 0x112, 0xF, 0xF);                   \
                DPPMAX(mx, 0x114, 0xF, 0xF); DPPMAX(mx, 0x118, 0xF, 0xF);                   \
                DPPMAX(mx, 0x142, 0xA, 0xF); DPPMAX(mx, 0x143, 0xC, 0xF);                   \
                int smx = __builtin_amdgcn_readlane(__float_as_int(mx), 63);                \
                int kk = ((smx >> 23) & 255) - 127;                                         \
                kk = kk < -124 ? -124 : (kk > 124 ? 124 : kk);                              \
                float sc = __int_as_float((unsigned)(127 - kk) << 23);                      \
                _Pragma("unroll")                                                           \
                for (int i2 = 0; i2 < 16; ++i2) cand[i2] *= sc;                             \
                if (act) sig##X += kk;                                                      \
            }                                                                               \
            _Pragma("unroll")                                                               \
            for (int i2 = 0; i2 < 16; ++i2) xs##X[i2] = act ? cand[i2] : xs##X[i2];         \
        }

        for (int ib = ibegU; ib < iendU; ib += 4) {
            PSTEP(A, 0) PSTEP(B, 0)
            PSTEP(A, 1) PSTEP(B, 1)
            PSTEP(A, 2) PSTEP(B, 2)
            PSTEP(A, 3) PSTEP(B, 3)
        }
#undef PSTEP
    }

    unsigned short* dstA = (bwd ? wsB : wsA) + ((size_t)c * CC + icA) * 64;
    unsigned short* dstB = (bwd ? wsB : wsA) + ((size_t)c * CC + icB) * 64;
#pragma unroll
    for (int kt2 = 0; kt2 < 2; ++kt2)
#pragma unroll
        for (int h = 0; h < 2; ++h)
#pragma unroll
            for (int r = 0; r < 4; ++r) {
                dstA[32 * kt2 + 16 * h + 4 * q + r] = bf16rne(xsA[kt2 * 8 + h * 4 + r]);
                dstB[32 * kt2 + 16 * h + 4 * q + r] = bf16rne(xsB[kt2 * 8 + h * 4 + r]);
            }
    if (!bwd && q == 0) {
        wsSig[c * CC + icA] = sigA;
        wsSig[c * CC + icB] = sigB;
    }
}

// ---------- kernel 3: parallel rank-1 combine, one block per chain (CC=128) ----------
// logZ/ln2 = sig_0 + sum_{i>=1} [sig_i + log2(b_i.a_{i-1}) - log2(b_i.1)] + log2(1.a_{C-1})
__global__ __launch_bounds__(256) void crf_combine(
    const unsigned short* __restrict__ wsA, const unsigned short* __restrict__ wsB,
    const int* __restrict__ wsSig, const float* __restrict__ wsS,
    float* __restrict__ out)
{
    __shared__ float eParts[4];
    const int tid = threadIdx.x, w = tid >> 6, lane = tid & 63;
    const int c = blockIdx.x;

    float Ep = 0.f;
#pragma unroll 4
    for (int k = 0; k < CC / 4; ++k) {
        const int i = w * (CC / 4) + k;
        if (i == 0) continue;
        float b  = __uint_as_float((unsigned)wsB[((size_t)c * CC + i) * 64 + lane] << 16);
        float ap = __uint_as_float((unsigned)wsA[((size_t)c * CC + i - 1) * 64 + lane] << 16);
        float d1 = b * ap, d0 = b;
#pragma unroll
        for (int xm = 32; xm >= 1; xm >>= 1) { d1 += __shfl_xor(d1, xm, 64); d0 += __shfl_xor(d0, xm, 64); }
        Ep += (float)wsSig[c * CC + i] + __builtin_amdgcn_logf(d1) - __builtin_amdgcn_logf(d0);
    }
    if (w == 0) Ep += (float)wsSig[c * CC];
    if (w == 3) {
        float al = __uint_as_float((unsigned)wsA[((size_t)c * CC + CC - 1) * 64 + lane] << 16);
#pragma unroll
        for (int xm = 32; xm >= 1; xm >>= 1) al += __shfl_xor(al, xm, 64);
        Ep += __builtin_amdgcn_logf(al);
    }
    if (lane == 0) eParts[w] = Ep;
    __syncthreads();
    if (tid == 0) {
        float E = eParts[0] + eParts[1] + eParts[2] + eParts[3];
        out[c] = C_LN2 * E - wsS[c];
    }
}

extern "C" void kernel_launch(void* const* d_in, const int* in_sizes, int n_in,
                              void* d_out, int out_size, void* d_ws, size_t ws_size,
                              hipStream_t stream) {
    const float* p  = (const float*)d_in[0];
    const int*   y  = (const int*)d_in[1];
    const int*   mk = (const int*)d_in[2];
    const float* tr = (const float*)d_in[3];
    float* out = (float*)d_out;

    float* wsS  = (float*)d_ws;                                          // 1 KB @ 0
    int*   wsL  = (int*)((char*)d_ws + 1024);                            // 1 KB @ 1024
    int*   wsSg = (int*)((char*)d_ws + 4096);                            // 128 KB @ 4 KB (BB*CC*4)
    unsigned char* wsLb = (unsigned char*)((char*)d_ws + 262144);        // 512 KB @ 256 KB
    unsigned short* wsA = (unsigned short*)((char*)d_ws + (1u << 20));   // 4 MB @ 1 MB (bf16)
    unsigned short* wsB = (unsigned short*)((char*)d_ws + (5u << 20));   // 4 MB @ 5 MB

    hipMemsetAsync(d_ws, 0, 1024, stream);                               // zero wsS only
    crf_len<<<dim3(BB), dim3(256), 0, stream>>>(mk, wsL);
    crf_lab<<<dim3(BB * TT / 64), dim3(256), 0, stream>>>(y, wsLb);
    crf_probe<<<dim3(16, CC / 4), dim3(256), 0, stream>>>(p, tr, wsL, wsA, wsB, wsSg);
    crf_gth<<<dim3(8, BB), dim3(256), 0, stream>>>(p, wsLb, mk, tr, wsS);
    crf_combine<<<dim3(BB), dim3(256), 0, stream>>>(wsA, wsB, wsSg, wsS, out);
}

// Round 12
// 307.955 us; speedup vs baseline: 1.0649x; 1.0649x over previous
//
#include <hip/hip_runtime.h>
#include <stdint.h>
#include <string.h>

#define BB 256
#define TT 2048
#define DD 64
#define CC 64          // chunks per chain (R9 best config, 312.2us)
#define SS 32          // steps per chunk
#define C_L2E 1.44269504f
#define C_LN2 0.69314718f
// log2(1 + 2^-9): compensates bf16 truncation bias of the pack, folded into exp
#define C_BIAS 0.0028174f

typedef short sh8  __attribute__((ext_vector_type(8)));
typedef float f32x4 __attribute__((ext_vector_type(4)));

union BU { sh8 v8; unsigned int u[4]; unsigned short s[8]; };

__device__ __forceinline__ float expf_fast(float x) { return __builtin_amdgcn_exp2f(x * C_L2E); }
__device__ __forceinline__ unsigned short bf16rne(float x) {
    unsigned int u = __float_as_uint(x);
    u += 0x7FFF + ((u >> 16) & 1u);
    return (unsigned short)(u >> 16);
}
__device__ __forceinline__ unsigned int pkbf(float hi, float lo) {
    return __builtin_amdgcn_perm(__float_as_uint(hi), __float_as_uint(lo), 0x07060302u);
}

#define DPPMAX(x, ctrl, rm, bm) { int _xi = __float_as_int(x);                              \
    int _yi = __builtin_amdgcn_update_dpp(_xi, _xi, ctrl, rm, bm, false);                   \
    x = fmaxf(x, __int_as_float(_yi)); }

// ---------- kernel 1: label extraction (bid < 8192) + lengths (bid >= 8192), merged ----------
// Both are independent read-only streams (lab over y, len over mask); merging removes one
// launch boundary. Bodies verbatim from the verified R7-R11 kernels.
__global__ __launch_bounds__(256) void crf_lab(
    const int* __restrict__ y, const int* __restrict__ mask,
    unsigned char* __restrict__ labsG, int* __restrict__ wsL)
{
    __shared__ int r4[4];
    const int bid = blockIdx.x;
    const int tid = threadIdx.x;

    if (bid < BB * TT / 64) {
        // ---- label extraction: 64 tokens/block, 16 lanes/token, 4 independent int4s ----
        const int g = tid & 15, sub = tid >> 4;          // sub 0..15
        const size_t base = (size_t)bid * 64;            // first token of block
        int4 v[4];
#pragma unroll
        for (int k = 0; k < 4; ++k)
            v[k] = ((const int4*)y)[(base + (size_t)k * 16 + sub) * 16 + g];  // 1 KB/wave/k
#pragma unroll
        for (int k = 0; k < 4; ++k) {
            int s = v[k].x * (4 * g) + v[k].y * (4 * g + 1)
                  + v[k].z * (4 * g + 2) + v[k].w * (4 * g + 3);
#pragma unroll
            for (int xm = 1; xm <= 8; xm <<= 1) s += __shfl_xor(s, xm, 16);
            if (g == 0) labsG[base + k * 16 + sub] = (unsigned char)s;
        }
    } else {
        // ---- lengths from mask (prefix property: L = #zeros) ----
        const int c = bid - BB * TT / 64;
        const int4* mrow = (const int4*)(mask + (size_t)c * TT);
        int4 a = mrow[tid * 2], b = mrow[tid * 2 + 1];
        int s = a.x + a.y + a.z + a.w + b.x + b.y + b.z + b.w;
#pragma unroll
        for (int xm = 32; xm >= 1; xm >>= 1) s += __shfl_xor(s, xm, 64);
        if ((tid & 63) == 0) r4[tid >> 6] = s;
        __syncthreads();
        if (tid == 0) wsL[c] = TT - (r4[0] + r4[1] + r4[2] + r4[3]);
    }
}

// ---------- kernel 2: rank-1 chunk probes (VERBATIM R9 body — session best) ----------
// Block: 4 waves = (ic0,fwd),(ic0,bwd),(ic1,fwd),(ic1,bwd) — same p slab for L2 reuse.
// Wave batches 16 chains (c = 16cg+ml). Per step: 8 MFMA 16x16x32 bf16; state f32[16]/lane,
// lambda-relabelled (lam = 32kt2+16h+4q+r); per-chain freeze; pow-2 renorm every 4 steps.
// Probe is ~78us invariant to issue depth (R0 d4 == R9 d2), wave count (R8 2x), segment
// coalescing (R10 LDS-staged 256B), and in-wave 2-chunk ILP (R11) — structural floor.
__global__ __launch_bounds__(256) void crf_probe(
    const float* __restrict__ p, const float* __restrict__ tr,
    const int* __restrict__ wsL,
    unsigned short* __restrict__ wsA, unsigned short* __restrict__ wsB, int* __restrict__ wsSig)
{
    const int tid = threadIdx.x, w = tid >> 6, lane = tid & 63;
    const int q = lane >> 4, ml = lane & 15;
    const int cg = blockIdx.x;
    const int ic = blockIdx.y * 2 + (w >> 1);
    const int bwd = w & 1;
    const int c = cg * 16 + ml;
    const int Lml = wsL[c];
    const int t0 = ic * SS, t1 = t0 + SS;
    const int ts = (ic == 0) ? 1 : t0;
    const float* prow = p + (size_t)c * TT * DD;

    // A fragments: fwd A = W^T (exp(T[lam][row])), bwd A = W (exp(T[row][lam]))
    BU A[4][2];
#pragma unroll
    for (int mt = 0; mt < 4; ++mt)
#pragma unroll
        for (int kt2 = 0; kt2 < 2; ++kt2)
#pragma unroll
            for (int j = 0; j < 8; ++j) {
                int lam = 32 * kt2 + 16 * (j >> 2) + 4 * q + (j & 3);
                float tv = bwd ? tr[(16 * mt + ml) * DD + lam] : tr[lam * DD + 16 * mt + ml];
                A[mt][kt2].s[j] = (short)bf16rne(expf_fast(tv));
            }

    // state xs[idx], idx = kt2*8 + h*4 + r  <->  lam = 32kt2+16h+4q+r
    float xs[16];
    if (!bwd && ic == 0) {           // exact start: u0 = exp(p[c,0,:])
#pragma unroll
        for (int k = 0; k < 4; ++k) {
            f32x4 v = *(const f32x4*)(prow + 16 * k + 4 * q);
#pragma unroll
            for (int r = 0; r < 4; ++r)
                xs[(k >> 1) * 8 + (k & 1) * 4 + r] = __builtin_amdgcn_exp2f(fmaf(v[r], C_L2E, C_BIAS));
        }
    } else {
#pragma unroll
        for (int i = 0; i < 16; ++i) xs[i] = 1.0f;
    }

    // wave max of L -> skip all-frozen step ranges
    int mL = Lml;
#pragma unroll
    for (int xm = 32; xm >= 1; xm >>= 1) { int o = __shfl_xor(mL, xm, 64); mL = o > mL ? o : mL; }
    int ibeg = 0, iend = SS;
    if (!bwd) { int ir = mL - t0; if (ir < 0) ir = 0; iend = (ir + 3) & ~3; if (iend > SS) iend = SS; }
    else      { int ir = t1 - mL; if (ir < 0) ir = 0; ibeg = ir & ~3; if (ibeg > SS) ibeg = SS; }

    int sig = 0;
    const f32x4 z4 = {0.f, 0.f, 0.f, 0.f};

    if (ibeg < iend) {
        f32x4 er[2][4];
#pragma unroll
        for (int s = 0; s < 2; ++s) {                 // preload steps ibeg, ibeg+1
            int i = ibeg + s;
            int t = bwd ? (t1 - 1 - i) : (t0 + i);
#pragma unroll
            for (int k = 0; k < 4; ++k)
                er[s][k] = *(const f32x4*)(prow + (size_t)t * DD + 16 * k + 4 * q);
        }
        for (int ib = ibeg; ib < iend; ib += 4) {
#pragma unroll
            for (int s = 0; s < 4; ++s) {             // static s -> slot s&1 static
                const int i = ib + s;
                const int t = bwd ? (t1 - 1 - i) : (t0 + i);
                const bool act = (t >= ts) && (t < Lml);
                float ee[4][4];
#pragma unroll
                for (int k = 0; k < 4; ++k)
#pragma unroll
                    for (int r = 0; r < 4; ++r)
                        ee[k][r] = __builtin_amdgcn_exp2f(fmaf(er[s & 1][k][r], C_L2E, C_BIAS));
                {   // prefetch step i+2 into slot s&1
                    int ipf = i + 2;
                    int tpf = bwd ? (t1 - 1 - ipf) : (t0 + ipf);
                    if (tpf < t0) tpf = t0;
                    if (tpf > t1 - 1) tpf = t1 - 1;
#pragma unroll
                    for (int k = 0; k < 4; ++k)
                        er[s & 1][k] = *(const f32x4*)(prow + (size_t)tpf * DD + 16 * k + 4 * q);
                }
                float cand[16];
                BU Bf[2];
                f32x4 acc[4];
                if (!bwd) {     // u' = diag(e) W^T u : scale on output
#pragma unroll
                    for (int kt2 = 0; kt2 < 2; ++kt2)
#pragma unroll
                        for (int jj = 0; jj < 4; ++jj)
                            Bf[kt2].u[jj] = pkbf(xs[kt2 * 8 + 2 * jj + 1], xs[kt2 * 8 + 2 * jj]);
#pragma unroll
                    for (int mt = 0; mt < 4; ++mt) {
                        acc[mt] = __builtin_amdgcn_mfma_f32_16x16x32_bf16(A[mt][0].v8, Bf[0].v8, z4, 0, 0, 0);
                        acc[mt] = __builtin_amdgcn_mfma_f32_16x16x32_bf16(A[mt][1].v8, Bf[1].v8, acc[mt], 0, 0, 0);
                    }
#pragma unroll
                    for (int mt = 0; mt < 4; ++mt)
#pragma unroll
                        for (int r = 0; r < 4; ++r)
                            cand[(mt >> 1) * 8 + (mt & 1) * 4 + r] = acc[mt][r] * ee[mt][r];
                } else {        // w' = W (e .* w) : scale on input
                    float xsc[16];
#pragma unroll
                    for (int kt2 = 0; kt2 < 2; ++kt2)
#pragma unroll
                        for (int h = 0; h < 2; ++h)
#pragma unroll
                            for (int r = 0; r < 4; ++r)
                                xsc[kt2 * 8 + h * 4 + r] = xs[kt2 * 8 + h * 4 + r] * ee[2 * kt2 + h][r];
#pragma unroll
                    for (int kt2 = 0; kt2 < 2; ++kt2)
#pragma unroll
                        for (int jj = 0; jj < 4; ++jj)
                            Bf[kt2].u[jj] = pkbf(xsc[kt2 * 8 + 2 * jj + 1], xsc[kt2 * 8 + 2 * jj]);
#pragma unroll
                    for (int mt = 0; mt < 4; ++mt) {
                        acc[mt] = __builtin_amdgcn_mfma_f32_16x16x32_bf16(A[mt][0].v8, Bf[0].v8, z4, 0, 0, 0);
                        acc[mt] = __builtin_amdgcn_mfma_f32_16x16x32_bf16(A[mt][1].v8, Bf[1].v8, acc[mt], 0, 0, 0);
                    }
#pragma unroll
                    for (int mt = 0; mt < 4; ++mt)
#pragma unroll
                        for (int r = 0; r < 4; ++r)
                            cand[(mt >> 1) * 8 + (mt & 1) * 4 + r] = acc[mt][r];
                }
                if (s == 3) {   // wave-uniform pow-2 renorm, per-chain sig
                    float mx = fabsf(cand[0]);
#pragma unroll
                    for (int i2 = 1; i2 < 16; ++i2) mx = fmaxf(mx, fabsf(cand[i2]));
                    DPPMAX(mx, 0x111, 0xF, 0xF); DPPMAX(mx, 0x112, 0xF, 0xF);
                    DPPMAX(mx, 0x114, 0xF, 0xF); DPPMAX(mx, 0x118, 0xF, 0xF);
                    DPPMAX(mx, 0x142, 0xA, 0xF); DPPMAX(mx, 0x143, 0xC, 0xF);
                    int smx = __builtin_amdgcn_readlane(__float_as_int(mx), 63);
                    int kk = ((smx >> 23) & 255) - 127;
                    kk = kk < -124 ? -124 : (kk > 124 ? 124 : kk);
                    float sc = __int_as_float((unsigned)(127 - kk) << 23);
#pragma unroll
                    for (int i2 = 0; i2 < 16; ++i2) cand[i2] *= sc;
                    if (act) sig += kk;
                }
#pragma unroll
                for (int i2 = 0; i2 < 16; ++i2) xs[i2] = act ? cand[i2] : xs[i2];
            }
        }
    }

    unsigned short* dst = (bwd ? wsB : wsA) + ((size_t)c * CC + ic) * 64;
#pragma unroll
    for (int kt2 = 0; kt2 < 2; ++kt2)
#pragma unroll
        for (int h = 0; h < 2; ++h)
#pragma unroll
            for (int r = 0; r < 4; ++r)
                dst[32 * kt2 + 16 * h + 4 * q + r] = bf16rne(xs[kt2 * 8 + h * 4 + r]);
    if (!bwd && q == 0) wsSig[c * CC + ic] = sig;
}

// ---------- kernel 3: score + rank-1 combine, one block per chain (gth merged in) ----------
// Score phase (was crf_gth): 8 tokens/thread, parallel gathers; p is L3-resident after
// probe's full sweep. No atomics / wsS / memset needed — score stays block-local.
// logZ/ln2 = sig_0 + sum_{i>=1} [sig_i + log2(b_i.a_{i-1}) - log2(b_i.1)] + log2(1.a_{C-1})
__global__ __launch_bounds__(256) void crf_combine(
    const float* __restrict__ p, const unsigned char* __restrict__ labsG,
    const int* __restrict__ mask, const float* __restrict__ tr,
    const unsigned short* __restrict__ wsA, const unsigned short* __restrict__ wsB,
    const int* __restrict__ wsSig, float* __restrict__ out)
{
    __shared__ float eParts[4], sParts[4];
    const int tid = threadIdx.x, w = tid >> 6, lane = tid & 63;
    const int c = blockIdx.x;
    const size_t cb = (size_t)c * TT;

    // ---- emission + transition score for this chain ----
    float s = 0.f;
#pragma unroll
    for (int k = 0; k < TT / 256; ++k) {
        const int tt = k * 256 + tid;
        const int m0 = mask[cb + tt];
        const int l0 = labsG[cb + tt];
        if (m0 == 0)                              // emission for valid token
            s += p[(cb + tt) * DD + l0];
        const int m1 = (tt + 1 < TT) ? mask[cb + tt + 1] : 1;
        if (m1 == 0)                              // pair (t,t+1) valid (prefix property)
            s += tr[l0 * DD + (int)labsG[cb + tt + 1]];
    }

    // ---- rank-1 combine ----
    float Ep = 0.f;
#pragma unroll
    for (int k = 0; k < 16; ++k) {
        const int i = w * 16 + k;
        if (i == 0) continue;
        float b  = __uint_as_float((unsigned)wsB[((size_t)c * CC + i) * 64 + lane] << 16);
        float ap = __uint_as_float((unsigned)wsA[((size_t)c * CC + i - 1) * 64 + lane] << 16);
        float d1 = b * ap, d0 = b;
#pragma unroll
        for (int xm = 32; xm >= 1; xm >>= 1) { d1 += __shfl_xor(d1, xm, 64); d0 += __shfl_xor(d0, xm, 64); }
        Ep += (float)wsSig[c * CC + i] + __builtin_amdgcn_logf(d1) - __builtin_amdgcn_logf(d0);
    }
    if (w == 0) Ep += (float)wsSig[c * CC];
    if (w == 3) {
        float al = __uint_as_float((unsigned)wsA[((size_t)c * CC + CC - 1) * 64 + lane] << 16);
#pragma unroll
        for (int xm = 32; xm >= 1; xm >>= 1) al += __shfl_xor(al, xm, 64);
        Ep += __builtin_amdgcn_logf(al);
    }
#pragma unroll
    for (int xm = 32; xm >= 1; xm >>= 1) s += __shfl_xor(s, xm, 64);
    if (lane == 0) { eParts[w] = Ep; sParts[w] = s; }
    __syncthreads();
    if (tid == 0) {
        float E = eParts[0] + eParts[1] + eParts[2] + eParts[3];
        float S = sParts[0] + sParts[1] + sParts[2] + sParts[3];
        out[c] = C_LN2 * E - S;
    }
}

extern "C" void kernel_launch(void* const* d_in, const int* in_sizes, int n_in,
                              void* d_out, int out_size, void* d_ws, size_t ws_size,
                              hipStream_t stream) {
    const float* p  = (const float*)d_in[0];
    const int*   y  = (const int*)d_in[1];
    const int*   mk = (const int*)d_in[2];
    const float* tr = (const float*)d_in[3];
    float* out = (float*)d_out;

    int*   wsL  = (int*)((char*)d_ws + 1024);                            // 1 KB @ 1024
    int*   wsSg = (int*)((char*)d_ws + 4096);                            // 64 KB @ 4 KB
    unsigned char* wsLb = (unsigned char*)((char*)d_ws + 131072);        // 512 KB @ 128 KB
    unsigned short* wsA = (unsigned short*)((char*)d_ws + (1u << 20));   // 2 MB @ 1 MB (bf16)
    unsigned short* wsB = (unsigned short*)((char*)d_ws + (3u << 20));   // 2 MB @ 3 MB

    crf_lab<<<dim3(BB * TT / 64 + BB), dim3(256), 0, stream>>>(y, mk, wsLb, wsL);
    crf_probe<<<dim3(16, CC / 2), dim3(256), 0, stream>>>(p, tr, wsL, wsA, wsB, wsSg);
    crf_combine<<<dim3(BB), dim3(256), 0, stream>>>(p, wsLb, mk, tr, wsA, wsB, wsSg, out);
}